// Round 1
// 234.304 us; speedup vs baseline: 1.0548x; 1.0548x over previous
//
#include <hip/hip_runtime.h>

#define B_ 2
#define N_ 2048
#define H_ 8
#define DH_ 32
#define E_ 65536
#define DIN_ 256
#define KT 256
#define ECAP 32
#define QSCALE 0.2550348872f           // log2(e)/sqrt(DH)
#define LOG2E 1.4426950408889634f
#define LOG2MIN -19.931568569324174f   // log2(1e-6)

typedef short bf16x8 __attribute__((ext_vector_type(8)));
typedef float floatx4 __attribute__((ext_vector_type(4)));

__device__ __forceinline__ unsigned short f2b(float f){
  union { float f; unsigned int u; } v; v.f = f;
  return (unsigned short)((v.u + 0x7fffu + ((v.u >> 16) & 1u)) >> 16);
}
__device__ __forceinline__ bf16x8 f8_to_bf(const float* p){
  float4 a = *(const float4*)p, b = *(const float4*)(p + 4);
  bf16x8 r;
  r[0] = (short)f2b(a.x); r[1] = (short)f2b(a.y); r[2] = (short)f2b(a.z); r[3] = (short)f2b(a.w);
  r[4] = (short)f2b(b.x); r[5] = (short)f2b(b.y); r[6] = (short)f2b(b.z); r[7] = (short)f2b(b.w);
  return r;
}
__device__ __forceinline__ unsigned int cvt_pk_bf16(float lo, float hi){
  unsigned int r;
  asm("v_cvt_pk_bf16_f32 %0, %1, %2" : "=v"(r) : "v"(lo), "v"(hi));
  return r;
}

// ---------------- prep: ffn (blocks 0..511) + fill (512..1023) + wT (1024..1279) ----------------
__global__ __launch_bounds__(256) void prep_kernel(
    const float* __restrict__ eattr,
    const float* __restrict__ w1, const float* __restrict__ b1,
    const float* __restrict__ w2, const float* __restrict__ b2,
    float* __restrict__ ea,
    const int* __restrict__ ei, int* __restrict__ cnt, unsigned int* __restrict__ pck,
    const float* __restrict__ w, unsigned short* __restrict__ wT)
{
  int bb = blockIdx.x, tid = threadIdx.x;
  if (bb < 512){
    __shared__ float W1[64], W2[64], Bv1[8], Bv2[8];
    if (tid < 64){ W1[tid] = w1[tid]; W2[tid] = w2[tid]; }
    if (tid < 8){ Bv1[tid] = b1[tid]; Bv2[tid] = b2[tid]; }
    __syncthreads();
    int gid = bb * 256 + tid;                 // b*E + e
    const float* ep = eattr + (size_t)gid * 8;
    float cur[8];
#pragma unroll
    for (int i = 0; i < 8; ++i) cur[i] = ep[i];
#pragma unroll
    for (int pass = 0; pass < 2; ++pass){
      float t[8];
#pragma unroll
      for (int j = 0; j < 8; ++j){
        float s = Bv1[j];
#pragma unroll
        for (int i = 0; i < 8; ++i) s += cur[i] * W1[i * 8 + j];
        t[j] = fmaxf(s, 0.f);
      }
#pragma unroll
      for (int j = 0; j < 8; ++j){
        float s = Bv2[j];
#pragma unroll
        for (int i = 0; i < 8; ++i) s += t[i] * W2[i * 8 + j];
        cur[j] = s;
      }
    }
    float* op = ea + (size_t)gid * 8;
#pragma unroll
    for (int j = 0; j < 8; ++j) op[j] = cur[j] * LOG2E;   // exp2-domain
  } else if (bb < 1024){
    int gid = (bb - 512) * 256 + tid;         // 0..131071
    int b = gid >> 16, e = gid & (E_ - 1);
    int u = ei[(size_t)b * 2 * E_ + e];
    int v = ei[(size_t)b * 2 * E_ + E_ + e];
    int bucket = ((b << 11) + u) * 8 + (v >> 8);
    int slot = atomicAdd(&cnt[bucket], 1);
    if (slot < ECAP) pck[(size_t)bucket * ECAP + slot] = ((unsigned int)e << 11) | (unsigned int)v;
  } else {
    int k = bb - 1024;                        // 0..255
    for (int c = tid; c < 768; c += 256)
      wT[(size_t)c * 256 + k] = f2b(w[(size_t)k * 768 + c]);
  }
}

// ---------------- QKV projection: (4096x256)@(256x768), MFMA; Q pre-scaled by log2e/sqrt(DH) ----------------
__global__ __launch_bounds__(256) void qkv_kernel(
    const float* __restrict__ x, const unsigned short* __restrict__ wT,
    const float* __restrict__ bias,
    unsigned short* __restrict__ Qb, unsigned short* __restrict__ Kb, unsigned short* __restrict__ Vt)
{
  int tid = threadIdx.x;
  int wave = tid >> 6, lane = tid & 63, m = lane & 15, quad = lane >> 4;
  int rowbase = blockIdx.x * 16;
  int colbase = blockIdx.y * 64 + wave * 16;
  floatx4 acc = {0.f, 0.f, 0.f, 0.f};
#pragma unroll
  for (int kb = 0; kb < 8; ++kb){
    bf16x8 af = f8_to_bf(x + (size_t)(rowbase + m) * DIN_ + kb * 32 + quad * 8);
    bf16x8 bf = *(const bf16x8*)(wT + (size_t)(colbase + m) * DIN_ + kb * 32 + quad * 8);
    acc = __builtin_amdgcn_mfma_f32_16x16x32_bf16(af, bf, acc, 0, 0, 0);
  }
  int ccol = colbase + m;
  int which = ccol >> 8, hh = (ccol >> 5) & 7, dh = ccol & 31;
  float bv = bias[ccol];
  int row0 = rowbase + quad * 4;
  int bidx = row0 >> 11, n0 = row0 & (N_ - 1);
  size_t bh = (size_t)(bidx * H_ + hh);
  if (which == 0){
#pragma unroll
    for (int r = 0; r < 4; ++r)
      Qb[(bh * N_ + n0 + r) * DH_ + dh] = f2b((acc[r] + bv) * QSCALE);
  } else if (which == 1){
#pragma unroll
    for (int r = 0; r < 4; ++r)
      Kb[(bh * N_ + n0 + r) * DH_ + dh] = f2b(acc[r] + bv);
  } else {
    ushort4 st;
    st.x = f2b(acc[0] + bv); st.y = f2b(acc[1] + bv);
    st.z = f2b(acc[2] + bv); st.w = f2b(acc[3] + bv);
    *(ushort4*)(Vt + (bh * DH_ + dh) * N_ + n0) = st;
  }
}

// ---------------- fused flash attention: barrier-free main loop, wave-private columns ----------------
// Each of the 4 waves owns cols [w*64, w*64+64) of the 16-row q-tile for the whole loop:
// QK^T write, edge-scatter, moire+softmax read are all wave-local (only lgkmcnt ordering needed).
// Per-wave online softmax (local m,l,O); one cross-wave rescaled merge at the end.
__global__ __launch_bounds__(256) void attn_kernel(
    const unsigned short* __restrict__ Qb, const unsigned short* __restrict__ Kb,
    const unsigned short* __restrict__ Vt, const float* __restrict__ adj,
    const float* __restrict__ ea, const int* __restrict__ cnt, const unsigned int* __restrict__ pck,
    const float* __restrict__ shifts, const float* __restrict__ widths,
    const float* __restrict__ selfW, float* __restrict__ out)
{
  __shared__ float S[4][16][68];          // wave-private 16x64 (+4 pad); stride 68 -> conflict-free b128 reads
  __shared__ float mfin[4][16], lfin[4][16];

  int bid = blockIdx.x;
  int qt = bid & 127, h = (bid >> 7) & 7, b = bid >> 10;
  int qbase = qt * 16;
  int tid = threadIdx.x, wave = tid >> 6, lane = tid & 63, m = lane & 15, quad = lane >> 4;
  float shift_h = shifts[h];
  float w_h = widths[h];
  float i2w_h = LOG2E / (2.f * w_h * w_h);
  float selfW_h = selfW[h] * LOG2E;
  size_t krow = (size_t)(b * H_ + h) * N_;
  size_t vrow = (size_t)(b * H_ + h) * DH_;
  bf16x8 qfrag = *(const bf16x8*)(Qb + (krow + qbase + m) * DH_ + quad * 8);
  float (*Sw)[68] = S[wave];

  int rr = lane >> 2, sl0 = lane & 3;     // scatter: 4 lanes per row
  const int* cntp = cnt + ((size_t)(b * N_) + qbase + rr) * 8;
  const unsigned int* pckp = pck + ((size_t)((b * N_ + qbase + rr) * 8)) * ECAP;
  const float* eabase = ea + (size_t)b * E_ * H_ + h;
  const float* adjp = adj + ((size_t)b * N_ + qbase + m) * N_ + wave * 64 + quad * 8;
  const unsigned short* vp0 = Vt + (vrow + m) * N_ + wave * 64 + quad * 8;
  const unsigned short* vp1 = Vt + (vrow + 16 + m) * N_ + wave * 64 + quad * 8;
  const unsigned short* kp  = Kb + (krow + wave * 64 + m) * DH_ + quad * 8;

  float mcur = -1e30f, lcur = 0.f;        // wave-local running max / sum for row m
  floatx4 oacc0 = {0.f, 0.f, 0.f, 0.f};
  floatx4 oacc1 = {0.f, 0.f, 0.f, 0.f};

  for (int kt = 0; kt < N_ / KT; ++kt){
    int k0 = kt * KT;
    // ---- QK^T: this wave's 64 cols x all 16 rows (+ self-loop on exact diagonal) ----
    int dq = qbase - k0 - wave * 64;
#pragma unroll
    for (int s = 0; s < 4; ++s){
      bf16x8 kf = *(const bf16x8*)(kp + (size_t)(k0 + s * 16) * DH_);
      floatx4 acc = {0.f, 0.f, 0.f, 0.f};
      acc = __builtin_amdgcn_mfma_f32_16x16x32_bf16(qfrag, kf, acc, 0, 0, 0);
      int t = s * 16 + m - dq;
#pragma unroll
      for (int r = 0; r < 4; ++r){
        float v = acc[r];
        if (t == quad * 4 + r) v += selfW_h;
        Sw[quad * 4 + r][s * 16 + m] = v;
      }
    }
    // ---- edge scatter, wave scans its rows' bucket and keeps only its own columns ----
    asm volatile("s_waitcnt lgkmcnt(0)" ::: "memory");
    {
      int nb = cntp[kt]; nb = nb > ECAP ? ECAP : nb;
      const unsigned int* pb = pckp + kt * ECAP;
      for (int slot = sl0; slot < nb; slot += 4){
        unsigned int pk = pb[slot];
        int vv = (int)(pk & (unsigned int)(N_ - 1));
        int c = vv - k0 - wave * 64;
        if ((unsigned)c < 64u){
          int e = (int)(pk >> 11);
          Sw[rr][c] += eabase[(size_t)e * H_];
        }
      }
    }
    asm volatile("s_waitcnt lgkmcnt(0)" ::: "memory");
    // ---- S rows to regs + direct adj loads; moire in registers ----
    const float* sp = &Sw[m][quad * 8];
    float4 s00 = *(const float4*)(sp);
    float4 s01 = *(const float4*)(sp + 4);
    float4 s10 = *(const float4*)(sp + 32);
    float4 s11 = *(const float4*)(sp + 36);
    const float* ap = adjp + k0;
    float4 a00 = *(const float4*)(ap);
    float4 a01 = *(const float4*)(ap + 4);
    float4 a10 = *(const float4*)(ap + 32);
    float4 a11 = *(const float4*)(ap + 36);
    bf16x8 vf00 = *(const bf16x8*)(vp0 + k0);
    bf16x8 vf01 = *(const bf16x8*)(vp1 + k0);
    bf16x8 vf10 = *(const bf16x8*)(vp0 + k0 + 32);
    bf16x8 vf11 = *(const bf16x8*)(vp1 + k0 + 32);
    float dd;
    dd = a00.x - shift_h; s00.x += fmaxf(-dd * dd * i2w_h, LOG2MIN);
    dd = a00.y - shift_h; s00.y += fmaxf(-dd * dd * i2w_h, LOG2MIN);
    dd = a00.z - shift_h; s00.z += fmaxf(-dd * dd * i2w_h, LOG2MIN);
    dd = a00.w - shift_h; s00.w += fmaxf(-dd * dd * i2w_h, LOG2MIN);
    dd = a01.x - shift_h; s01.x += fmaxf(-dd * dd * i2w_h, LOG2MIN);
    dd = a01.y - shift_h; s01.y += fmaxf(-dd * dd * i2w_h, LOG2MIN);
    dd = a01.z - shift_h; s01.z += fmaxf(-dd * dd * i2w_h, LOG2MIN);
    dd = a01.w - shift_h; s01.w += fmaxf(-dd * dd * i2w_h, LOG2MIN);
    dd = a10.x - shift_h; s10.x += fmaxf(-dd * dd * i2w_h, LOG2MIN);
    dd = a10.y - shift_h; s10.y += fmaxf(-dd * dd * i2w_h, LOG2MIN);
    dd = a10.z - shift_h; s10.z += fmaxf(-dd * dd * i2w_h, LOG2MIN);
    dd = a10.w - shift_h; s10.w += fmaxf(-dd * dd * i2w_h, LOG2MIN);
    dd = a11.x - shift_h; s11.x += fmaxf(-dd * dd * i2w_h, LOG2MIN);
    dd = a11.y - shift_h; s11.y += fmaxf(-dd * dd * i2w_h, LOG2MIN);
    dd = a11.z - shift_h; s11.z += fmaxf(-dd * dd * i2w_h, LOG2MIN);
    dd = a11.w - shift_h; s11.w += fmaxf(-dd * dd * i2w_h, LOG2MIN);
    // ---- wave-local row max (over this wave's 64 cols only) ----
    float lm = fmaxf(fmaxf(fmaxf(s00.x, s00.y), fmaxf(s00.z, s00.w)),
                     fmaxf(fmaxf(s01.x, s01.y), fmaxf(s01.z, s01.w)));
    lm = fmaxf(lm, fmaxf(fmaxf(fmaxf(s10.x, s10.y), fmaxf(s10.z, s10.w)),
                         fmaxf(fmaxf(s11.x, s11.y), fmaxf(s11.z, s11.w))));
    lm = fmaxf(lm, __shfl_xor(lm, 16));
    lm = fmaxf(lm, __shfl_xor(lm, 32));
    float mnew = fmaxf(mcur, lm);
    float al = exp2f(mcur - mnew);
    mcur = mnew;
    float al0 = __shfl(al, quad * 4 + 0);
    float al1 = __shfl(al, quad * 4 + 1);
    float al2 = __shfl(al, quad * 4 + 2);
    float al3 = __shfl(al, quad * 4 + 3);
    oacc0[0] *= al0; oacc0[1] *= al1; oacc0[2] *= al2; oacc0[3] *= al3;
    oacc1[0] *= al0; oacc1[1] *= al1; oacc1[2] *= al2; oacc1[3] *= al3;
    // ---- P = exp2(S - m), cvt_pk pack, PV MFMA, row-sum ----
    float ps = 0.f, p0, p1;
    union { bf16x8 v; unsigned int u[4]; } P;
    p0 = exp2f(s00.x - mcur); p1 = exp2f(s00.y - mcur); ps += p0 + p1; P.u[0] = cvt_pk_bf16(p0, p1);
    p0 = exp2f(s00.z - mcur); p1 = exp2f(s00.w - mcur); ps += p0 + p1; P.u[1] = cvt_pk_bf16(p0, p1);
    p0 = exp2f(s01.x - mcur); p1 = exp2f(s01.y - mcur); ps += p0 + p1; P.u[2] = cvt_pk_bf16(p0, p1);
    p0 = exp2f(s01.z - mcur); p1 = exp2f(s01.w - mcur); ps += p0 + p1; P.u[3] = cvt_pk_bf16(p0, p1);
    oacc0 = __builtin_amdgcn_mfma_f32_16x16x32_bf16(P.v, vf00, oacc0, 0, 0, 0);
    oacc1 = __builtin_amdgcn_mfma_f32_16x16x32_bf16(P.v, vf01, oacc1, 0, 0, 0);
    p0 = exp2f(s10.x - mcur); p1 = exp2f(s10.y - mcur); ps += p0 + p1; P.u[0] = cvt_pk_bf16(p0, p1);
    p0 = exp2f(s10.z - mcur); p1 = exp2f(s10.w - mcur); ps += p0 + p1; P.u[1] = cvt_pk_bf16(p0, p1);
    p0 = exp2f(s11.x - mcur); p1 = exp2f(s11.y - mcur); ps += p0 + p1; P.u[2] = cvt_pk_bf16(p0, p1);
    p0 = exp2f(s11.z - mcur); p1 = exp2f(s11.w - mcur); ps += p0 + p1; P.u[3] = cvt_pk_bf16(p0, p1);
    oacc0 = __builtin_amdgcn_mfma_f32_16x16x32_bf16(P.v, vf10, oacc0, 0, 0, 0);
    oacc1 = __builtin_amdgcn_mfma_f32_16x16x32_bf16(P.v, vf11, oacc1, 0, 0, 0);
    ps += __shfl_xor(ps, 16);
    ps += __shfl_xor(ps, 32);
    lcur = lcur * al + ps;
  }

  // ---- single cross-wave merge: O = sum_w exp2(m_w - m_g) O_w ; l likewise ----
  if (quad == 0){ mfin[wave][m] = mcur; lfin[wave][m] = lcur; }
  float* Ow = &S[wave][0][0];             // each wave parks O in its OWN region (no race pre-barrier)
#pragma unroll
  for (int r = 0; r < 4; ++r){
    Ow[(quad * 4 + r) * 32 + m]      = oacc0[r];
    Ow[(quad * 4 + r) * 32 + 16 + m] = oacc1[r];
  }
  __syncthreads();
  const float* Sv = &S[0][0][0];
#pragma unroll
  for (int ii = 0; ii < 2; ++ii){
    int i = tid + ii * 256;
    int r = i >> 5, dcol = i & 31;
    float m0 = mfin[0][r], m1 = mfin[1][r], m2 = mfin[2][r], m3 = mfin[3][r];
    float mg = fmaxf(fmaxf(m0, m1), fmaxf(m2, m3));
    float w0 = exp2f(m0 - mg), w1 = exp2f(m1 - mg);
    float w2 = exp2f(m2 - mg), w3 = exp2f(m3 - mg);
    int o_idx = r * 32 + dcol;
    float o = Sv[o_idx] * w0 + Sv[1088 + o_idx] * w1
            + Sv[2176 + o_idx] * w2 + Sv[3264 + o_idx] * w3;
    float l = lfin[0][r] * w0 + lfin[1][r] * w1 + lfin[2][r] * w2 + lfin[3][r] * w3;
    out[((size_t)b * N_ + qbase + r) * (H_ * DH_) + h * DH_ + dcol] = o / l;
  }
}

extern "C" void kernel_launch(void* const* d_in, const int* in_sizes, int n_in,
                              void* d_out, int out_size, void* d_ws, size_t ws_size,
                              hipStream_t stream)
{
  const float* x      = (const float*)d_in[0];
  const float* adj    = (const float*)d_in[1];
  const float* eattr  = (const float*)d_in[2];
  const float* qkvw   = (const float*)d_in[3];
  const float* qkvb   = (const float*)d_in[4];
  const float* ew1    = (const float*)d_in[5];
  const float* eb1    = (const float*)d_in[6];
  const float* ew2    = (const float*)d_in[7];
  const float* eb2    = (const float*)d_in[8];
  const float* shifts = (const float*)d_in[9];
  const float* widths = (const float*)d_in[10];
  const float* selfW  = (const float*)d_in[11];
  const int*   ei     = (const int*)d_in[12];
  float* out = (float*)d_out;

  char* ws = (char*)d_ws;
  unsigned short* Qb  = (unsigned short*)(ws);                        // 2 MB
  unsigned short* Kb  = (unsigned short*)(ws + ((size_t)2 << 20));    // 2 MB
  unsigned short* Vt  = (unsigned short*)(ws + ((size_t)4 << 20));    // 2 MB
  unsigned short* wT  = (unsigned short*)(ws + ((size_t)6 << 20));    // 384 KB
  float*          ea  = (float*)(ws + ((size_t)7 << 20));             // 4 MB
  int*            cnt = (int*)(ws + ((size_t)11 << 20));              // 128 KB
  unsigned int*  pck  = (unsigned int*)(ws + ((size_t)12 << 20));     // 4 MB (total 16 MB)

  hipMemsetAsync(cnt, 0, (size_t)B_ * N_ * 8 * sizeof(int), stream);
  hipLaunchKernelGGL(prep_kernel, dim3(1280), dim3(256), 0, stream,
                     eattr, ew1, eb1, ew2, eb2, ea, ei, cnt, pck, qkvw, wT);
  hipLaunchKernelGGL(qkv_kernel, dim3(256, 12), dim3(256), 0, stream, x, wT, qkvb, Qb, Kb, Vt);
  hipLaunchKernelGGL(attn_kernel, dim3(B_ * H_ * (N_ / 16)), dim3(256), 0, stream,
                     Qb, Kb, Vt, adj, ea, cnt, pck, shifts, widths, selfW, out);
}